// Round 2
// baseline (207.656 us; speedup 1.0000x reference)
//
#include <hip/hip_runtime.h>
#include <math.h>

typedef unsigned short US;
typedef __attribute__((ext_vector_type(8))) __bf16 bf16x8;
typedef __attribute__((ext_vector_type(4))) float f32x4;
typedef __attribute__((ext_vector_type(4))) unsigned short us4;

#define MFMA16(a, b, c) __builtin_amdgcn_mfma_f32_16x16x32_bf16(a, b, c, 0, 0, 0)

__device__ __forceinline__ US f2bf(float f) {
  union { float f; unsigned u; } v; v.f = f;
  unsigned r = v.u + 0x7fffu + ((v.u >> 16) & 1u);
  return (US)(r >> 16);
}

__device__ __forceinline__ void gload16(const void* g, void* l) {
  __builtin_amdgcn_global_load_lds(
      (const __attribute__((address_space(1))) unsigned int*)g,
      (__attribute__((address_space(3))) unsigned int*)l, 16, 0, 0);
}

// ---------------- convert f32 -> bf16 staging ----------------
// element ranges: [0..4194304) x -> xb ; [4194304..7340032) Wq|Wk|Wv -> wqkv ;
// [7340032..8388608) Wo -> wob.  8388608 total / (256 thr * 4 elem) = 8192 blocks.
__global__ __launch_bounds__(256) void convert_k(
    const float* __restrict__ x, const float* __restrict__ Wq,
    const float* __restrict__ Wk, const float* __restrict__ Wv,
    const float* __restrict__ Wo,
    US* __restrict__ xb, US* __restrict__ wqkv, US* __restrict__ wob) {
  long i = (long)blockIdx.x * blockDim.x + threadIdx.x;
  long e4 = i * 4;
  if (e4 >= 8388608L) return;
  const float* src; US* dst;
  if (e4 < 4194304L) { src = x + e4; dst = xb + e4; }
  else if (e4 < 7340032L) {
    long off = e4 - 4194304L;
    dst = wqkv + off;
    src = (off < 1048576L) ? Wq + off
        : (off < 2097152L ? Wk + (off - 1048576L) : Wv + (off - 2097152L));
  } else {
    long off = e4 - 7340032L;
    src = Wo + off; dst = wob + off;
  }
  float4 v = *(const float4*)src;
  us4 o; o.x = f2bf(v.x); o.y = f2bf(v.y); o.z = f2bf(v.z); o.w = f2bf(v.w);
  *(us4*)dst = o;
}

// ---------------- 128x128 bf16 GEMM (m97 structure) ----------------
// C[m][n] = sum_k A[m][k] * BT[n][k]
// MODE 0: QKV epilogue (bias, Q scale, Q/K [B,H,S,L] bf16, V transposed [B,H,L,S] bf16)
// MODE 1: f32 out + bias
template <int MODE>
__global__ __launch_bounds__(256) void gemm128(
    const US* __restrict__ A, const US* __restrict__ BT,
    int K, int lda, int ldb, int N,
    const float* __restrict__ b0, const float* __restrict__ b1,
    const float* __restrict__ b2,
    US* __restrict__ oQ, US* __restrict__ oK, US* __restrict__ oV,
    float* __restrict__ oF) {
  __shared__ __align__(16) US As[128 * 32];
  __shared__ __align__(16) US Bs[128 * 32];
  const int tid = threadIdx.x, lane = tid & 63;
  const int w = tid >> 6, wr = w >> 1, wc = w & 1;
  const int m0 = blockIdx.x * 128, n0 = blockIdx.y * 128;
  f32x4 acc[4][4] = {};
  const int r0 = tid >> 2, c0 = (tid & 3) * 8;  // staging: row, col (elements)

  for (int kt = 0; kt < K; kt += 32) {
    gload16(A + (size_t)(m0 + r0) * lda + kt + c0, As + tid * 8);
    gload16(A + (size_t)(m0 + r0 + 64) * lda + kt + c0, As + (tid + 256) * 8);
    gload16(BT + (size_t)(n0 + r0) * ldb + kt + c0, Bs + tid * 8);
    gload16(BT + (size_t)(n0 + r0 + 64) * ldb + kt + c0, Bs + (tid + 256) * 8);
    __syncthreads();
    bf16x8 af[4], bfm[4];
#pragma unroll
    for (int i = 0; i < 4; ++i)
      af[i] = *(const bf16x8*)(As + (wr * 64 + i * 16 + (lane & 15)) * 32 + (lane >> 4) * 8);
#pragma unroll
    for (int j = 0; j < 4; ++j)
      bfm[j] = *(const bf16x8*)(Bs + (wc * 64 + j * 16 + (lane & 15)) * 32 + (lane >> 4) * 8);
#pragma unroll
    for (int i = 0; i < 4; ++i)
#pragma unroll
      for (int j = 0; j < 4; ++j)
        acc[i][j] = MFMA16(af[i], bfm[j], acc[i][j]);
    __syncthreads();
  }

#pragma unroll
  for (int i = 0; i < 4; ++i) {
#pragma unroll
    for (int j = 0; j < 4; ++j) {
#pragma unroll
      for (int r = 0; r < 4; ++r) {
        int m = m0 + wr * 64 + i * 16 + (lane >> 4) * 4 + r;
        int n = n0 + wc * 64 + j * 16 + (lane & 15);
        float v = acc[i][j][r];
        if (MODE == 0) {
          int bb = m >> 11, s = m & 2047;
          int sec = n >> 10, idx = n & 1023;
          int h = idx >> 6, l = idx & 63;
          size_t bhsl = (((size_t)bb * 16 + h) * 2048 + s) * 64 + l;
          if (sec == 0)      oQ[bhsl] = f2bf((v + b0[idx]) * 0.125f);
          else if (sec == 1) oK[bhsl] = f2bf(v + b1[idx]);
          else oV[(((size_t)bb * 16 + h) * 64 + l) * 2048 + s] = f2bf(v + b2[idx]);
        } else {
          oF[(size_t)m * N + n] = v + b0[n];
        }
      }
    }
  }
}

// ---------------- causal flash attention ----------------
// grid: 32 bh * 32 qtiles; block 256 (4 waves x 16 q-rows); KVBLK=64
__global__ __launch_bounds__(256) void attn_k(
    const US* __restrict__ Qb, const US* __restrict__ Kb,
    const US* __restrict__ Vtb, US* __restrict__ zb) {
  __shared__ __align__(16) US Ks[64 * 64];
  __shared__ __align__(16) US Vs[64 * 64];
  __shared__ __align__(16) US Ps[4][16 * 72];
  const int tid = threadIdx.x, lane = tid & 63, w = tid >> 6;
  const int bh = blockIdx.x >> 5;
  const int qt = 31 - (blockIdx.x & 31);  // heavy tiles first
  const US* Qp = Qb + ((size_t)bh * 2048 + qt * 64) * 64;
  const US* Kp = Kb + (size_t)bh * 2048 * 64;
  const US* Vp = Vtb + (size_t)bh * 64 * 2048;

  bf16x8 aq[2];
  {
    int qrow = w * 16 + (lane & 15);
#pragma unroll
    for (int kk = 0; kk < 2; ++kk)
      aq[kk] = *(const bf16x8*)(Qp + qrow * 64 + kk * 32 + (lane >> 4) * 8);
  }
  f32x4 o[4] = {};
  float mrow[4], lrow[4];
#pragma unroll
  for (int r = 0; r < 4; ++r) { mrow[r] = -INFINITY; lrow[r] = 0.f; }

  for (int kt = 0; kt <= qt; ++kt) {
#pragma unroll
    for (int half = 0; half < 2; ++half) {
      int c = half * 256 + tid;       // 512 chunks of 16B per tile
      int row = c >> 3, col = c & 7;
      int off = row * 128 + col * 16;
      int soff = off ^ ((row & 7) << 4);  // XOR swizzle (G4)
      *(int4*)((char*)Ks + soff) =
          *(const int4*)((const char*)Kp + ((size_t)(kt * 64 + row)) * 128 + col * 16);
      *(int4*)((char*)Vs + soff) =
          *(const int4*)((const char*)Vp + (size_t)row * 4096 + kt * 128 + col * 16);
    }
    __syncthreads();

    f32x4 sc[4];
#pragma unroll
    for (int nt = 0; nt < 4; ++nt) {
      f32x4 s = {0.f, 0.f, 0.f, 0.f};
#pragma unroll
      for (int kk = 0; kk < 2; ++kk) {
        int rr = nt * 16 + (lane & 15);
        int off = rr * 128 + kk * 64 + (lane >> 4) * 16;
        off ^= (rr & 7) << 4;
        bf16x8 bkf = *(const bf16x8*)((const char*)Ks + off);
        s = MFMA16(aq[kk], bkf, s);
      }
      sc[nt] = s;
    }

    if (kt == qt) {  // diagonal tile: causal mask
#pragma unroll
      for (int nt = 0; nt < 4; ++nt)
#pragma unroll
        for (int r = 0; r < 4; ++r) {
          int qr = w * 16 + (lane >> 4) * 4 + r;
          int kv = nt * 16 + (lane & 15);
          if (kv > qr) sc[nt][r] = -INFINITY;
        }
    }

    // online softmax; row r lives in 16 lanes sharing (lane>>4)
#pragma unroll
    for (int r = 0; r < 4; ++r) {
      float mx = fmaxf(fmaxf(sc[0][r], sc[1][r]), fmaxf(sc[2][r], sc[3][r]));
#pragma unroll
      for (int d = 1; d < 16; d <<= 1) mx = fmaxf(mx, __shfl_xor(mx, d));
      float mnew = fmaxf(mrow[r], mx);
      float scale = __expf(mrow[r] - mnew);
      float ssum = 0.f;
#pragma unroll
      for (int nt = 0; nt < 4; ++nt) {
        float p = __expf(sc[nt][r] - mnew);
        sc[nt][r] = p;
        ssum += p;
      }
#pragma unroll
      for (int d = 1; d < 16; d <<= 1) ssum += __shfl_xor(ssum, d);
      lrow[r] = lrow[r] * scale + ssum;
      mrow[r] = mnew;
#pragma unroll
      for (int nt = 0; nt < 4; ++nt) o[nt][r] *= scale;
    }

    // P -> LDS (per-wave, padded stride 72 -> conflict-free b128 reads)
    US* pp = &Ps[w][0];
#pragma unroll
    for (int r = 0; r < 4; ++r)
#pragma unroll
      for (int nt = 0; nt < 4; ++nt) {
        int prow = (lane >> 4) * 4 + r, pcol = nt * 16 + (lane & 15);
        pp[prow * 72 + pcol] = f2bf(sc[nt][r]);
      }

    // PV
#pragma unroll
    for (int kk = 0; kk < 2; ++kk) {
      bf16x8 pa = *(const bf16x8*)(pp + (lane & 15) * 72 + kk * 32 + (lane >> 4) * 8);
#pragma unroll
      for (int nt = 0; nt < 4; ++nt) {
        int rr = nt * 16 + (lane & 15);
        int off = rr * 128 + kk * 64 + (lane >> 4) * 16;
        off ^= (rr & 7) << 4;
        bf16x8 bvf = *(const bf16x8*)((const char*)Vs + off);
        o[nt] = MFMA16(pa, bvf, o[nt]);
      }
    }
    __syncthreads();
  }

  const int b = bh >> 4, h = bh & 15;
#pragma unroll
  for (int r = 0; r < 4; ++r) {
    float inv = 1.0f / lrow[r];
    int s = qt * 64 + w * 16 + (lane >> 4) * 4 + r;
#pragma unroll
    for (int nt = 0; nt < 4; ++nt) {
      int d = nt * 16 + (lane & 15);
      zb[((size_t)b * 2048 + s) * 1024 + h * 64 + d] = f2bf(o[nt][r] * inv);
    }
  }
}

extern "C" void kernel_launch(void* const* d_in, const int* in_sizes, int n_in,
                              void* d_out, int out_size, void* d_ws, size_t ws_size,
                              hipStream_t stream) {
  (void)in_sizes; (void)n_in; (void)out_size; (void)ws_size;
  const float* x  = (const float*)d_in[0];
  // d_in[1] = mask (exact causal tril by construction; implemented analytically)
  const float* Wq = (const float*)d_in[2];
  const float* bq = (const float*)d_in[3];
  const float* Wk = (const float*)d_in[4];
  const float* bk = (const float*)d_in[5];
  const float* Wv = (const float*)d_in[6];
  const float* bv = (const float*)d_in[7];
  const float* Wo = (const float*)d_in[8];
  const float* bo = (const float*)d_in[9];
  char* ws = (char*)d_ws;
  // Workspace layout (total 40 MB). zb ALIASES xb: xb is dead after gemm128<0>,
  // attn_k (later in stream order) writes zb there.
  US* xb   = (US*)(ws);              // [4096][1024]      8 MB   (phase 1-2)
  US* zb   = (US*)(ws);              // [B,S,H*L]         8 MB   (phase 3-4)
  US* wqkv = (US*)(ws + 8388608);    // [3072][1024]      6 MB
  US* wob  = (US*)(ws + 14680064);   // [1024][1024]      2 MB
  US* Qb   = (US*)(ws + 16777216);   // [B,H,S,L]         8 MB
  US* Kb   = (US*)(ws + 25165824);   // [B,H,S,L]         8 MB
  US* Vtb  = (US*)(ws + 33554432);   // [B,H,L,S]         8 MB
  float* out = (float*)d_out;

  convert_k<<<dim3(8192), dim3(256), 0, stream>>>(x, Wq, Wk, Wv, Wo, xb, wqkv, wob);
  gemm128<0><<<dim3(32, 24), dim3(256), 0, stream>>>(
      xb, wqkv, 1024, 1024, 1024, 3072, bq, bk, bv, Qb, Kb, Vtb, (float*)nullptr);
  attn_k<<<dim3(1024), dim3(256), 0, stream>>>(Qb, Kb, Vtb, zb);
  gemm128<1><<<dim3(32, 8), dim3(256), 0, stream>>>(
      zb, wob, 1024, 1024, 1024, 1024, bo, (const float*)nullptr, (const float*)nullptr,
      (US*)nullptr, (US*)nullptr, (US*)nullptr, out);
}